// Round 17
// baseline (238.690 us; speedup 1.0000x reference)
//
#include <hip/hip_runtime.h>
#include <hip/hip_bf16.h>

// SparseFactorisationDense: out = relu(scaling * (x @ (k0*m0) @ (k1*m1) @ (k2*m2)) + bias)
// B=8192, D=U=2048.
// R17 = R16/R13 skeleton with 32x32x16 MFMA + conflict-free full-row LDS:
//   - LDS rows = full BK=64 (128B = one bank sweep) -> 32x32 fragment reads
//     (32 consecutive rows/lane-group) are 2-way/free with a 3-bit slot XOR:
//     phys_slot = (ks*2+lh) ^ (row&7). R8's 32x32 failure was 64B-row geometry
//     (6.29M conflicts); the fragment mapping + epilogue are R8-verified.
//   - MFMA term per CU per K-tile: 2483 -> 2066 cyc (8.07cyc/32768FLOP); LDS
//     term unchanged -> serial floor ~4370 cyc/tile.
//   - staging: gload dest lane->(row base+l>>3, slot l&7); source k pre-XORed
//     with (l>>3)&7 (both-sides involution, rule #21).
//   - R13 interval ledger: reads hit buf b, DMA hits buf b^1, one
//     LGK0+VM0+BAR per tile. T1 XCD swizzle, packed epilogue unchanged.

typedef __attribute__((ext_vector_type(8)))  short  short8;
typedef __attribute__((ext_vector_type(8)))  ushort ushort8v;
typedef __attribute__((ext_vector_type(16))) float  f32x16;

#define KD 2048
#define ND 2048

__device__ __forceinline__ ushort f2b(float f) {      // fp32 -> bf16 RNE
    union { float f; unsigned u; } v; v.f = f;
    unsigned r = v.u + 0x7fffu + ((v.u >> 16) & 1u);
    return (ushort)(r >> 16);
}

__device__ __forceinline__ void gload16(const ushort* g, ushort* l) {
    __builtin_amdgcn_global_load_lds(
        (const __attribute__((address_space(1))) void*)g,
        (__attribute__((address_space(3))) void*)l, 16, 0, 0);
}

// ---- x: fp32 -> bf16, 8 elems/thread
__global__ __launch_bounds__(256)
void convx(const float* __restrict__ x, ushort* __restrict__ xb)
{
    const size_t i = (size_t)blockIdx.x * 256 + threadIdx.x;
    const float4* src = reinterpret_cast<const float4*>(x) + i * 2;
    const float4 f0 = src[0], f1 = src[1];
    ushort8v u;
    u[0]=f2b(f0.x); u[1]=f2b(f0.y); u[2]=f2b(f0.z); u[3]=f2b(f0.w);
    u[4]=f2b(f1.x); u[5]=f2b(f1.y); u[6]=f2b(f1.z); u[7]=f2b(f1.w);
    reinterpret_cast<ushort8v*>(xb)[i] = u;
}

// ---- masked-weight transpose+convert for all 3 layers (blockIdx.z picks layer)
__global__ __launch_bounds__(256)
void convT3(const float* __restrict__ k0w, const float* __restrict__ k1w,
            const float* __restrict__ k2w, const float* __restrict__ m0w,
            const float* __restrict__ m1w, const float* __restrict__ m2w,
            ushort* __restrict__ wbT)
{
    const int z = blockIdx.z;
    const float* kw = z == 0 ? k0w : (z == 1 ? k1w : k2w);
    const float* mw = z == 0 ? m0w : (z == 1 ? m1w : m2w);
    ushort* o = wbT + (size_t)z * KD * ND;

    __shared__ ushort t[32][36];
    const int tid = threadIdx.x;
    const int bk = blockIdx.x * 32, bn = blockIdx.y * 32;
    {
        const int r = tid >> 3, c = (tid & 7) * 4;
        const size_t g = (size_t)(bk + r) * ND + bn + c;
        const float4 kv = *reinterpret_cast<const float4*>(kw + g);
        const float4 mv = *reinterpret_cast<const float4*>(mw + g);
        t[r][c + 0] = f2b(kv.x * mv.x);
        t[r][c + 1] = f2b(kv.y * mv.y);
        t[r][c + 2] = f2b(kv.z * mv.z);
        t[r][c + 3] = f2b(kv.w * mv.w);
    }
    __syncthreads();
    {
        const int n = tid >> 3, kq = (tid & 7) * 4;
        ushort4 ov;
        ov.x = t[kq + 0][n]; ov.y = t[kq + 1][n];
        ov.z = t[kq + 2][n]; ov.w = t[kq + 3][n];
        *reinterpret_cast<ushort4*>(&o[(size_t)(bn + n) * KD + bk + kq]) = ov;
    }
}

// ============ 256x256 GEMM, 32x32x16 MFMA, full-row LDS, 3-bit swizzle ============
// C[M][N] = A[M][K] @ BT[N][K]^T, all bf16 in, fp32 accum.
template<int EPI>
__global__ __launch_bounds__(512, 2)
void gemm256(const ushort* __restrict__ A, const ushort* __restrict__ BT,
             void* __restrict__ Cout,
             const float* __restrict__ scaling, const float* __restrict__ bias)
{
    // [buf][op 0=A 1=B][row*64 + k]  = 2*2*256*64*2B = 128 KiB
    __shared__ ushort S[2][2][256 * 64];

    const int tid  = threadIdx.x;
    const int lane = tid & 63;
    const int wid  = tid >> 6;                 // 0..7
    const int wr   = wid >> 2, wc = wid & 3;   // 2x4 wave grid: 128x64 per wave
    const int l31  = lane & 31;
    const int lh   = lane >> 5;                // k-half within kstep (8 elems)
    // T1: bijective XCD swizzle (256 blocks % 8 XCDs == 0)
    const int id   = blockIdx.x;
    const int swz  = (id & 7) * 32 + (id >> 3);
    const int bn   = (swz & 7) * 256;          // 8 N-blocks
    const int bm   = (swz >> 3) * 256;         // 32 M-blocks
    const int srow = lane >> 3;                // staging: 8 rows / gload
    const int wrow = wid * 32;                 // this wave's 32-row staging slice
    // both-sides involution (3-bit): phys 16B slot = logical ^ (row&7)
    const int ssw  = ((lane & 7) ^ (srow & 7)) * 8;   // staged source k-offset
    const int rk3  = l31 & 7;                          // fragment-read XOR key

    f32x16 acc[4][2] = {};

#define STAGE32(op, bufl, tile, G, g0) do {                                          \
    gload16(G + (size_t)((g0) + wrow +  0 + srow) * KD + (tile)*64 + ssw,            \
            &S[bufl][op][(wrow +  0) * 64]);                                         \
    gload16(G + (size_t)((g0) + wrow +  8 + srow) * KD + (tile)*64 + ssw,            \
            &S[bufl][op][(wrow +  8) * 64]);                                         \
    gload16(G + (size_t)((g0) + wrow + 16 + srow) * KD + (tile)*64 + ssw,            \
            &S[bufl][op][(wrow + 16) * 64]);                                         \
    gload16(G + (size_t)((g0) + wrow + 24 + srow) * KD + (tile)*64 + ssw,            \
            &S[bufl][op][(wrow + 24) * 64]);                                         \
  } while (0)

#define BAR()  asm volatile("s_barrier" ::: "memory")
#define VM0()  asm volatile("s_waitcnt vmcnt(0)" ::: "memory")
#define LGK0() asm volatile("s_waitcnt lgkmcnt(0)" ::: "memory")
#define PRI1() __builtin_amdgcn_s_setprio(1)
#define PRI0() __builtin_amdgcn_s_setprio(0)

// fragment reads: row = tile_row + l31; 16B slot = (ks*2+lh) ^ (row&7)
#define FA32(bufl, mt, ks) (*(const short8*)&S[bufl][0][                              \
        (wr*128 + (mt)*32 + l31)*64 + ((((ks)*2 + lh) ^ rk3) * 8)])
#define FB32(bufl, nt, ks) (*(const short8*)&S[bufl][1][                              \
        (wc*64  + (nt)*32 + l31)*64 + ((((ks)*2 + lh) ^ rk3) * 8)])

#define MF32(a_, b_, c_) __builtin_amdgcn_mfma_f32_32x32x16_bf16(a_, b_, c_, 0, 0, 0)

// One sub-phase: 12 ds_read_b128 (2 ksteps) + STG + 16 MFMA (operand-swapped,
// R8-verified mapping).
#define SUBPH(bufl, ka, kb, STG) do {                                                 \
    short8 b0a = FB32(bufl,0,ka), b1a = FB32(bufl,1,ka);                              \
    short8 a0a = FA32(bufl,0,ka), a1a = FA32(bufl,1,ka),                              \
           a2a = FA32(bufl,2,ka), a3a = FA32(bufl,3,ka);                              \
    short8 b0b = FB32(bufl,0,kb), b1b = FB32(bufl,1,kb);                              \
    short8 a0b = FA32(bufl,0,kb), a1b = FA32(bufl,1,kb),                              \
           a2b = FA32(bufl,2,kb), a3b = FA32(bufl,3,kb);                              \
    STG;                                                                              \
    PRI1();                                                                           \
    acc[0][0]=MF32(b0a,a0a,acc[0][0]); acc[0][1]=MF32(b1a,a0a,acc[0][1]);             \
    acc[1][0]=MF32(b0a,a1a,acc[1][0]); acc[1][1]=MF32(b1a,a1a,acc[1][1]);             \
    acc[2][0]=MF32(b0a,a2a,acc[2][0]); acc[2][1]=MF32(b1a,a2a,acc[2][1]);             \
    acc[3][0]=MF32(b0a,a3a,acc[3][0]); acc[3][1]=MF32(b1a,a3a,acc[3][1]);             \
    acc[0][0]=MF32(b0b,a0b,acc[0][0]); acc[0][1]=MF32(b1b,a0b,acc[0][1]);             \
    acc[1][0]=MF32(b0b,a1b,acc[1][0]); acc[1][1]=MF32(b1b,a1b,acc[1][1]);             \
    acc[2][0]=MF32(b0b,a2b,acc[2][0]); acc[2][1]=MF32(b1b,a2b,acc[2][1]);             \
    acc[3][0]=MF32(b0b,a3b,acc[3][0]); acc[3][1]=MF32(b1b,a3b,acc[3][1]);             \
    PRI0();                                                                           \
  } while (0)

    // ---- prologue: stage tile 0 (A+B) into buf0, drain, barrier
    STAGE32(0, 0, 0, A, bm); STAGE32(1, 0, 0, BT, bn);
    VM0();
    BAR();

    // ---- main: tiles 0..30 compute from buf(t&1), stage t+1 into buf^1
    for (int t = 0; t < 31; ++t) {
        const int bf = t & 1;
        SUBPH(bf, 0, 1, STAGE32(0, bf ^ 1, t + 1, A,  bm));
        SUBPH(bf, 2, 3, STAGE32(1, bf ^ 1, t + 1, BT, bn));
        LGK0(); VM0(); BAR();
    }
    // ---- tail: tile 31 (buf1), no staging, no barrier
    SUBPH(1, 0, 1, );
    SUBPH(1, 2, 3, );

    // ---- epilogue (R8-verified swapped 32x32 layout): lane row m = l31;
    // reg-quad r -> n-cols nt*32 + lh*4 + r*8 + {0..3}
    const float sc = EPI ? scaling[0] : 0.f;
#pragma unroll
    for (int mt = 0; mt < 4; ++mt) {
        const size_t grow = (size_t)(bm + wr * 128 + mt * 32 + l31);
#pragma unroll
        for (int nt = 0; nt < 2; ++nt) {
#pragma unroll
            for (int r = 0; r < 4; ++r) {
                const int gcol = bn + wc * 64 + nt * 32 + lh * 4 + r * 8;
                if constexpr (EPI) {
                    const float4 bv = *reinterpret_cast<const float4*>(bias + gcol);
                    float4 v;
                    v.x = fmaxf(fmaf(sc, acc[mt][nt][4*r+0], bv.x), 0.f);
                    v.y = fmaxf(fmaf(sc, acc[mt][nt][4*r+1], bv.y), 0.f);
                    v.z = fmaxf(fmaf(sc, acc[mt][nt][4*r+2], bv.z), 0.f);
                    v.w = fmaxf(fmaf(sc, acc[mt][nt][4*r+3], bv.w), 0.f);
                    *reinterpret_cast<float4*>((float*)Cout + grow * ND + gcol) = v;
                } else {
                    ushort4 v;
                    v.x = f2b(acc[mt][nt][4*r+0]); v.y = f2b(acc[mt][nt][4*r+1]);
                    v.z = f2b(acc[mt][nt][4*r+2]); v.w = f2b(acc[mt][nt][4*r+3]);
                    *reinterpret_cast<ushort4*>((ushort*)Cout + grow * ND + gcol) = v;
                }
            }
        }
    }
#undef STAGE32
#undef SUBPH
#undef MF32
#undef FA32
#undef FB32
}

extern "C" void kernel_launch(void* const* d_in, const int* in_sizes, int n_in,
                              void* d_out, int out_size, void* d_ws, size_t ws_size,
                              hipStream_t stream)
{
    // inputs: x, k0, k1, k2, m0, m1, m2, scaling, bias
    const float* x    = (const float*)d_in[0];
    const float* k0w  = (const float*)d_in[1];
    const float* k1w  = (const float*)d_in[2];
    const float* k2w  = (const float*)d_in[3];
    const float* m0w  = (const float*)d_in[4];
    const float* m1w  = (const float*)d_in[5];
    const float* m2w  = (const float*)d_in[6];
    const float* sc   = (const float*)d_in[7];
    const float* bias = (const float*)d_in[8];

    const int Md = in_sizes[0] / KD;               // 8192
    const size_t NE = (size_t)Md * KD;             // 16.7M elems

    // d_out (64MB fp32): [act1 bf16 32MB][x_bf16 32MB]; GEMM3 overwrites all.
    ushort* act1 = (ushort*)d_out;
    ushort* xb   = (ushort*)d_out + NE;
    float*  out  = (float*)d_out;
    // ws: [act2 bf16 32MB][wbT0 8MB][wbT1 8MB][wbT2 8MB] = 56MB
    ushort* act2 = (ushort*)d_ws;
    ushort* wbT  = (ushort*)d_ws + NE;

    dim3 bl(256);
    dim3 gX(NE / (256 * 8));                       // 8192
    dim3 gT(KD / 32, ND / 32, 3);                  // (64,64,3)
    dim3 gG((ND / 256) * (Md / 256)), bG(512);     // 256 blocks 1D (XCD swizzle inside)

    convx <<<gX, bl, 0, stream>>>(x, xb);
    convT3<<<gT, bl, 0, stream>>>(k0w, k1w, k2w, m0w, m1w, m2w, wbT);

    gemm256<0><<<gG, bG, 0, stream>>>(xb,   wbT,                     act1, nullptr, nullptr);
    gemm256<0><<<gG, bG, 0, stream>>>(act1, wbT + (size_t)KD * ND,     act2, nullptr, nullptr);
    gemm256<1><<<gG, bG, 0, stream>>>(act2, wbT + (size_t)2 * KD * ND, out,  sc, bias);
}